// Round 1
// baseline (2963.420 us; speedup 1.0000x reference)
//
#include <hip/hip_runtime.h>

// SigWassersteinMetric: depth-4 path signature, C=10, T=256.
//   original: (4096, 256, 10) f32; generated: (1024, 256, 10) f32; sample_idx: (1024,)
//
// ROUND-15: pass-split grid for full occupancy.
//   - R14 ran 1024 blocks x (2 sequential passes): 4096 waves / 1024 SIMDs =
//     4 waves/SIMD resident -> VALUBusy 75%, Occupancy 31%. The two passes only
//     interact through a LINEAR reduction (signed difference), so the serial
//     pass loop was artificial.
//   - Now: 2048 blocks, block bp = (pair b = bp>>1, pass = bp&1). Each block
//     computes one path's signature with sign baked in (+orig / -gen) and
//     writes its own ws row (plain stores). 8 blocks/CU x 4 waves = 32
//     waves/CU = HW cap (VGPR<=64, LDS 12.3KB x 8 = 98KB <= 160KB).
//   - sum kernel reduces 2048 rows (grid y=64): +~45MB reads ~= +8us, against
//     a predicted ~45-50us accum saving from closing the 25% issue-idle gap.
//   - Micro: folded per-q constant muls into per-step t1b/t2b (-2 inst/step).
//
// MODEL (R6/R9/R13/R14): ~134M VALU wave-inst; measured FP32 issue ceiling
// (m07 ubench 103TF) = 8.06e11 wave-inst/s -> 166us floor. R14 = 220us at
// VALUBusy 75% / 4 waves/SIMD. Prediction here: VALUBusy -> ~90%, accum
// -> ~170us (LDS pipe: ~30 issue-cyc/step/wave x 32 waves ~ co-saturates).
//
// Horner-factored Chen step (verified rounds 2/4-13):
//   A2 = S2 + (S1 + v/4) (x) v/3 ;  B2 = S2 + (S1 + v/3) (x) v/2
//   A3 = S3 + A2 (x) v/2 ;  S4' = S4 + A3 (x) v ;  S3' = S3 + B2 (x) v
//   S2' = S2 + (S1 + v/2) (x) v ;  S1 closed-form in epilogue.
#define T_LEN 256
#define C_DIM 10
#define NSTEP 255
#define BSZ   1024
#define NPAIR 1024
#define D1 10
#define D2 100
#define D3 1000
#define DTOT 11110
#define PATH_ELEMS (T_LEN * C_DIM)   // 2560
#define DX_ELEMS (NSTEP * C_DIM)     // 2550
#define DXROW 12                     // padded dx row stride (48 B, 16B-aligned)

__global__ __launch_bounds__(256, 8)
void sig_accum_kernel(
    const float* __restrict__ original,
    const float* __restrict__ generated,
    const int* __restrict__ sample_idx,
    float* __restrict__ ws, int nrep, int store_mode)
{
    const int tid  = threadIdx.x;
    const int bp   = blockIdx.x;         // 0 .. 2*NPAIR-1
    const int b    = bp >> 1;            // pair index
    const int pass = bp & 1;             // 0 = generated (-), 1 = original (+)
    const float sgn = pass ? 1.0f : -1.0f;

    __shared__ float s_dx[NSTEP * DXROW];  // 12240 B

    const float* path = pass
        ? original + (size_t)sample_idx[b] * PATH_ELEMS
        : generated + (size_t)b * PATH_ELEMS;

    for (int idx = tid; idx < DX_ELEMS; idx += 256) {
        int t = idx / C_DIM, c = idx - t * C_DIM;
        s_dx[t * DXROW + c] = path[idx + C_DIM] - path[idx];
    }
    __syncthreads();

    const int mbase = 2 * tid;               // valid tid<250
    const int k0  = mbase / 100;             // 0..4
    const int ij0 = mbase - k0 * 100;        // even
    const int ia  = ij0 / 10;
    const int j0  = ij0 - ia * 10;           // even -> (j0, j0+1) same decade

    float s1a = 0.0f;
    float s2[2] = {0.0f, 0.0f};
    float s3[4] = {0.0f, 0.0f, 0.0f, 0.0f};   // [q]=(ij0+q,k0), [2+q]=(ij0+q,k0+5)
    float acc[4][10];
    #pragma unroll
    for (int r = 0; r < 4; ++r)
        #pragma unroll
        for (int l = 0; l < 10; ++l) acc[r][l] = 0.0f;

    if (tid < 250) {
        const float* vrow = s_dx;
        #pragma unroll 2
        for (int t = 0; t < NSTEP; ++t, vrow += DXROW) {
            const float4 va = *(const float4*)(vrow);       // v0..v3 (uniform)
            const float4 vb = *(const float4*)(vrow + 4);   // v4..v7 (uniform)
            const float2 vc = *(const float2*)(vrow + 8);   // v8,v9  (uniform)
            const float2 vjp = *(const float2*)(vrow + j0); // vj for q0,q1
            const float via = vrow[ia];
            const float vk0 = vrow[k0];
            const float vk1 = vrow[k0 + 5];

            const float vv[10] = {va.x, va.y, va.z, va.w,
                                  vb.x, vb.y, vb.z, vb.w, vc.x, vc.y};
            const float vk0h = vk0 * 0.5f;
            const float vk1h = vk1 * 0.5f;
            const float t3  = s1a + via * 0.5f;
            const float t1b = (s1a + via * 0.25f) * (1.0f / 3.0f);
            const float t2b = (s1a + via * (1.0f / 3.0f)) * 0.5f;

            #pragma unroll
            for (int q = 0; q < 2; ++q) {
                const float vjq = (q == 0) ? vjp.x : vjp.y;
                const float a2 = fmaf(t1b, vjq, s2[q]);
                const float b2 = fmaf(t2b, vjq, s2[q]);
                s2[q] = fmaf(t3, vjq, s2[q]);

                const float a3x = fmaf(a2, vk0h, s3[q]);
                s3[q] = fmaf(b2, vk0, s3[q]);
                #pragma unroll
                for (int l = 0; l < 10; ++l)
                    acc[q][l] = fmaf(a3x, vv[l], acc[q][l]);

                const float a3y = fmaf(a2, vk1h, s3[2 + q]);
                s3[2 + q] = fmaf(b2, vk1, s3[2 + q]);
                #pragma unroll
                for (int l = 0; l < 10; ++l)
                    acc[2 + q][l] = fmaf(a3y, vv[l], acc[2 + q][l]);
            }
            s1a += via;
        }
    }

    // ---- Epilogue: signed single-path row ----
    if (store_mode) {
        float* row = ws + (size_t)bp * DTOT;
        if (tid < D1)
            row[tid] = sgn * (path[(T_LEN - 1) * C_DIM + tid] - path[tid]);
        if (tid < 50) {       // k0 == 0 threads own ij0 = 2*tid
            row[D1 + ij0]     = sgn * s2[0];
            row[D1 + ij0 + 1] = sgn * s2[1];
        }
        if (tid < 250) {
            #pragma unroll
            for (int ch = 0; ch < 2; ++ch) {          // ch=0 -> k0, ch=1 -> k0+5
                const int kk = k0 + 5 * ch;
                #pragma unroll
                for (int q = 0; q < 2; ++q) {
                    const int idx3 = (ij0 + q) * 10 + kk;
                    row[D1 + D2 + idx3] = sgn * s3[ch * 2 + q];
                    float* p4 = row + D1 + D2 + D3 + (size_t)idx3 * 10;
                    #pragma unroll
                    for (int l = 0; l < 10; l += 2)
                        *(float2*)&p4[l] = make_float2(sgn * acc[ch * 2 + q][l],
                                                       sgn * acc[ch * 2 + q][l + 1]);
                }
            }
        }
    } else {
        float* base = ws + (size_t)(b % nrep) * DTOT;
        if (tid < D1)
            atomicAdd(&base[tid],
                      sgn * (path[(T_LEN - 1) * C_DIM + tid] - path[tid]));
        if (tid < 50) {
            atomicAdd(&base[D1 + ij0],     sgn * s2[0]);
            atomicAdd(&base[D1 + ij0 + 1], sgn * s2[1]);
        }
        if (tid < 250) {
            #pragma unroll
            for (int ch = 0; ch < 2; ++ch) {
                const int kk = k0 + 5 * ch;
                #pragma unroll
                for (int q = 0; q < 2; ++q) {
                    const int idx3 = (ij0 + q) * 10 + kk;
                    atomicAdd(&base[D1 + D2 + idx3], sgn * s3[ch * 2 + q]);
                    #pragma unroll
                    for (int l = 0; l < 10; ++l)
                        atomicAdd(&base[D1 + D2 + D3 + idx3 * 10 + l],
                                  sgn * acc[ch * 2 + q][l]);
                }
            }
        }
    }
}

// Stage 1: block sums 32 rows for a float2 d-tile (coalesced), atomically
// accumulates into accvec[DTOT]. Grid: (ceil(5555/256), nrows/32).
__global__ __launch_bounds__(256) void sig_sum_kernel(
    const float* __restrict__ ws, float* __restrict__ accvec)
{
    const int d2 = blockIdx.x * 256 + threadIdx.x;   // DTOT/2 = 5555
    if (d2 >= DTOT / 2) return;
    const float* p = ws + (size_t)(blockIdx.y * 32) * DTOT + 2 * d2;
    float sx = 0.0f, sy = 0.0f;
    #pragma unroll
    for (int r = 0; r < 32; ++r) {
        const float2 v = *(const float2*)(p + (size_t)r * DTOT);
        sx += v.x; sy += v.y;
    }
    atomicAdd(&accvec[2 * d2], sx);
    atomicAdd(&accvec[2 * d2 + 1], sy);
}

// Stage 2: sum of squares -> sumsq; last block writes the norm.
__global__ __launch_bounds__(256) void sig_sumsq_kernel(
    const float* __restrict__ accvec, float* __restrict__ sumsq,
    unsigned int* __restrict__ counter, float* __restrict__ out, int nblocks)
{
    const int d = blockIdx.x * 256 + threadIdx.x;
    float s = 0.0f;
    if (d < DTOT) { float v = accvec[d]; s = v * v; }
    for (int off = 32; off > 0; off >>= 1) s += __shfl_down(s, off, 64);
    __shared__ float red[4];
    __shared__ unsigned int lastflag;
    if ((threadIdx.x & 63) == 0) red[threadIdx.x >> 6] = s;
    __syncthreads();
    if (threadIdx.x == 0) {
        atomicAdd(sumsq, red[0] + red[1] + red[2] + red[3]);
        __threadfence();
        lastflag = (atomicAdd(counter, 1u) == (unsigned int)(nblocks - 1));
    }
    __syncthreads();
    if (threadIdx.x == 0 && lastflag) {
        __threadfence();
        out[0] = sqrtf(*(volatile float*)sumsq) * (1.0f / (float)BSZ);
    }
}

// Fallback reduce for small-ws atomic-replica modes.
__global__ __launch_bounds__(256) void sig_reduce_kernel(
    const float* __restrict__ ws, int nrows, float* __restrict__ sumsq,
    unsigned int* __restrict__ counter, float* __restrict__ out, int nblocks)
{
    const int d = blockIdx.x * 256 + threadIdx.x;
    float s = 0.0f;
    if (d < DTOT) {
        for (int r = 0; r < nrows; ++r) s += ws[(size_t)r * DTOT + d];
        s = s * s;
    }
    for (int off = 32; off > 0; off >>= 1) s += __shfl_down(s, off, 64);
    __shared__ float red[4];
    __shared__ unsigned int lastflag;
    if ((threadIdx.x & 63) == 0) red[threadIdx.x >> 6] = s;
    __syncthreads();
    if (threadIdx.x == 0) {
        atomicAdd(sumsq, red[0] + red[1] + red[2] + red[3]);
        __threadfence();
        lastflag = (atomicAdd(counter, 1u) == (unsigned int)(nblocks - 1));
    }
    __syncthreads();
    if (threadIdx.x == 0 && lastflag) {
        __threadfence();
        out[0] = sqrtf(*(volatile float*)sumsq) * (1.0f / (float)BSZ);
    }
}

extern "C" void kernel_launch(void* const* d_in, const int* in_sizes, int n_in,
                              void* d_out, int out_size, void* d_ws, size_t ws_size,
                              hipStream_t stream) {
    const float* original   = (const float*)d_in[0];
    const float* generated  = (const float*)d_in[1];
    const int*   sample_idx = (const int*)d_in[2];
    float* out = (float*)d_out;
    float* ws  = (float*)d_ws;

    // Layouts:
    //  split: rows [0, 2*NPAIR*DTOT), accvec [+DTOT), sumsq [+1), counter [+1)
    //  store: rows [0, NPAIR*DTOT),   accvec [+DTOT), sumsq [+1), counter [+1)
    const size_t need_split = ((size_t)(2 * NPAIR + 1) * DTOT + 2) * sizeof(float);
    const size_t need_store = ((size_t)(NPAIR + 1) * DTOT + 2) * sizeof(float);

    if (ws_size >= need_split) {
        // Primary: each pass-block writes its own signed row (no atomics).
        float* accvec = ws + (size_t)2 * NPAIR * DTOT;
        float* sumsq  = accvec + DTOT;
        unsigned int* counter = (unsigned int*)(sumsq + 1);
        hipMemsetAsync(accvec, 0, (DTOT + 2) * sizeof(float), stream);
        sig_accum_kernel<<<2 * NPAIR, 256, 0, stream>>>(original, generated,
                                                        sample_idx, ws, 1, 1);
        dim3 g1((DTOT / 2 + 255) / 256, 2 * NPAIR / 32);
        sig_sum_kernel<<<g1, 256, 0, stream>>>(ws, accvec);
        const int nb2 = (DTOT + 255) / 256;
        sig_sumsq_kernel<<<nb2, 256, 0, stream>>>(accvec, sumsq, counter, out, nb2);
    } else if (ws_size >= need_store) {
        // Pair-atomic: the two pass-blocks of a pair accumulate into one row.
        float* accvec = ws + (size_t)NPAIR * DTOT;
        float* sumsq  = accvec + DTOT;
        unsigned int* counter = (unsigned int*)(sumsq + 1);
        hipMemsetAsync(ws, 0, need_store, stream);
        sig_accum_kernel<<<2 * NPAIR, 256, 0, stream>>>(original, generated,
                                                        sample_idx, ws, NPAIR, 0);
        dim3 g1((DTOT / 2 + 255) / 256, NPAIR / 32);
        sig_sum_kernel<<<g1, 256, 0, stream>>>(ws, accvec);
        const int nb2 = (DTOT + 255) / 256;
        sig_sumsq_kernel<<<nb2, 256, 0, stream>>>(accvec, sumsq, counter, out, nb2);
    } else {
        int nrep = 1;
        if (ws_size >= ((size_t)64 * DTOT + 2) * sizeof(float)) nrep = 64;
        else if (ws_size >= ((size_t)8 * DTOT + 2) * sizeof(float)) nrep = 8;
        float* sumsq = ws + (size_t)nrep * DTOT;
        unsigned int* counter = (unsigned int*)(sumsq + 1);
        hipMemsetAsync(ws, 0, ((size_t)nrep * DTOT + 2) * sizeof(float), stream);
        sig_accum_kernel<<<2 * NPAIR, 256, 0, stream>>>(original, generated,
                                                        sample_idx, ws, nrep, 0);
        const int nb2 = (DTOT + 255) / 256;
        sig_reduce_kernel<<<nb2, 256, 0, stream>>>(ws, nrep, sumsq, counter, out, nb2);
    }
}

// Round 2
// 283.775 us; speedup vs baseline: 10.4428x; 10.4428x over previous
//
#include <hip/hip_runtime.h>

// SigWassersteinMetric: depth-4 path signature, C=10, T=256.
//   original: (4096, 256, 10) f32; generated: (1024, 256, 10) f32; sample_idx: (1024,)
//
// ROUND-16: R15 pass-split grid, WITHOUT the launch-bounds occupancy pin.
//   - R15's __launch_bounds__(256,8) set a hard 64-VGPR cap; the allocator
//     couldn't fit (~66 needed), spilled acc[4][10] to scratch -> VGPR 32,
//     9.5 GB scratch writes, 2.9 ms. Plain bounds let it land at ~60 VGPRs,
//     which ALREADY permits 8 waves/SIMD (occupancy step at vgpr=64).
//   - Grid stays 2048 blocks: block bp = (pair b = bp>>1, pass = bp&1), each
//     block computes one path's signature with sign baked in (+orig/-gen) and
//     writes its own ws row. 8 blocks/CU x 4 waves = 32 waves/CU cap.
//   - sum kernel reduces 2048 rows (grid y=64).
//
// MODEL (R6/R9/R13/R14): ~134M VALU wave-inst; measured FP32 issue ceiling
// (m07 ubench 103TF) = 8.06e11 wave-inst/s -> 166us floor. R14 = 220us at
// VALUBusy 75% / 4 waves/SIMD (grid-limited). Prediction: VALUBusy ~90%,
// accum ~170us, total ~250us.
//
// Horner-factored Chen step (verified rounds 2/4-13):
//   A2 = S2 + (S1 + v/4) (x) v/3 ;  B2 = S2 + (S1 + v/3) (x) v/2
//   A3 = S3 + A2 (x) v/2 ;  S4' = S4 + A3 (x) v ;  S3' = S3 + B2 (x) v
//   S2' = S2 + (S1 + v/2) (x) v ;  S1 closed-form in epilogue.
#define T_LEN 256
#define C_DIM 10
#define NSTEP 255
#define BSZ   1024
#define NPAIR 1024
#define D1 10
#define D2 100
#define D3 1000
#define DTOT 11110
#define PATH_ELEMS (T_LEN * C_DIM)   // 2560
#define DX_ELEMS (NSTEP * C_DIM)     // 2550
#define DXROW 12                     // padded dx row stride (48 B, 16B-aligned)

__global__ __launch_bounds__(256)
void sig_accum_kernel(
    const float* __restrict__ original,
    const float* __restrict__ generated,
    const int* __restrict__ sample_idx,
    float* __restrict__ ws, int nrep, int store_mode)
{
    const int tid  = threadIdx.x;
    const int bp   = blockIdx.x;         // 0 .. 2*NPAIR-1
    const int b    = bp >> 1;            // pair index
    const int pass = bp & 1;             // 0 = generated (-), 1 = original (+)
    const float sgn = pass ? 1.0f : -1.0f;

    __shared__ float s_dx[NSTEP * DXROW];  // 12240 B

    const float* path = pass
        ? original + (size_t)sample_idx[b] * PATH_ELEMS
        : generated + (size_t)b * PATH_ELEMS;

    for (int idx = tid; idx < DX_ELEMS; idx += 256) {
        int t = idx / C_DIM, c = idx - t * C_DIM;
        s_dx[t * DXROW + c] = path[idx + C_DIM] - path[idx];
    }
    __syncthreads();

    const int mbase = 2 * tid;               // valid tid<250
    const int k0  = mbase / 100;             // 0..4
    const int ij0 = mbase - k0 * 100;        // even
    const int ia  = ij0 / 10;
    const int j0  = ij0 - ia * 10;           // even -> (j0, j0+1) same decade

    float s1a = 0.0f;
    float s2[2] = {0.0f, 0.0f};
    float s3[4] = {0.0f, 0.0f, 0.0f, 0.0f};   // [q]=(ij0+q,k0), [2+q]=(ij0+q,k0+5)
    float acc[4][10];
    #pragma unroll
    for (int r = 0; r < 4; ++r)
        #pragma unroll
        for (int l = 0; l < 10; ++l) acc[r][l] = 0.0f;

    if (tid < 250) {
        const float* vrow = s_dx;
        #pragma unroll 2
        for (int t = 0; t < NSTEP; ++t, vrow += DXROW) {
            const float4 va = *(const float4*)(vrow);       // v0..v3 (uniform)
            const float4 vb = *(const float4*)(vrow + 4);   // v4..v7 (uniform)
            const float2 vc = *(const float2*)(vrow + 8);   // v8,v9  (uniform)
            const float2 vjp = *(const float2*)(vrow + j0); // vj for q0,q1
            const float via = vrow[ia];
            const float vk0 = vrow[k0];
            const float vk1 = vrow[k0 + 5];

            const float vv[10] = {va.x, va.y, va.z, va.w,
                                  vb.x, vb.y, vb.z, vb.w, vc.x, vc.y};
            const float vk0h = vk0 * 0.5f;
            const float vk1h = vk1 * 0.5f;
            const float t3  = s1a + via * 0.5f;
            const float t1b = (s1a + via * 0.25f) * (1.0f / 3.0f);
            const float t2b = (s1a + via * (1.0f / 3.0f)) * 0.5f;

            #pragma unroll
            for (int q = 0; q < 2; ++q) {
                const float vjq = (q == 0) ? vjp.x : vjp.y;
                const float a2 = fmaf(t1b, vjq, s2[q]);
                const float b2 = fmaf(t2b, vjq, s2[q]);
                s2[q] = fmaf(t3, vjq, s2[q]);

                const float a3x = fmaf(a2, vk0h, s3[q]);
                s3[q] = fmaf(b2, vk0, s3[q]);
                #pragma unroll
                for (int l = 0; l < 10; ++l)
                    acc[q][l] = fmaf(a3x, vv[l], acc[q][l]);

                const float a3y = fmaf(a2, vk1h, s3[2 + q]);
                s3[2 + q] = fmaf(b2, vk1, s3[2 + q]);
                #pragma unroll
                for (int l = 0; l < 10; ++l)
                    acc[2 + q][l] = fmaf(a3y, vv[l], acc[2 + q][l]);
            }
            s1a += via;
        }
    }

    // ---- Epilogue: signed single-path row ----
    if (store_mode) {
        float* row = ws + (size_t)bp * DTOT;
        if (tid < D1)
            row[tid] = sgn * (path[(T_LEN - 1) * C_DIM + tid] - path[tid]);
        if (tid < 50) {       // k0 == 0 threads own ij0 = 2*tid
            row[D1 + ij0]     = sgn * s2[0];
            row[D1 + ij0 + 1] = sgn * s2[1];
        }
        if (tid < 250) {
            #pragma unroll
            for (int ch = 0; ch < 2; ++ch) {          // ch=0 -> k0, ch=1 -> k0+5
                const int kk = k0 + 5 * ch;
                #pragma unroll
                for (int q = 0; q < 2; ++q) {
                    const int idx3 = (ij0 + q) * 10 + kk;
                    row[D1 + D2 + idx3] = sgn * s3[ch * 2 + q];
                    float* p4 = row + D1 + D2 + D3 + (size_t)idx3 * 10;
                    #pragma unroll
                    for (int l = 0; l < 10; l += 2)
                        *(float2*)&p4[l] = make_float2(sgn * acc[ch * 2 + q][l],
                                                       sgn * acc[ch * 2 + q][l + 1]);
                }
            }
        }
    } else {
        float* base = ws + (size_t)(b % nrep) * DTOT;
        if (tid < D1)
            atomicAdd(&base[tid],
                      sgn * (path[(T_LEN - 1) * C_DIM + tid] - path[tid]));
        if (tid < 50) {
            atomicAdd(&base[D1 + ij0],     sgn * s2[0]);
            atomicAdd(&base[D1 + ij0 + 1], sgn * s2[1]);
        }
        if (tid < 250) {
            #pragma unroll
            for (int ch = 0; ch < 2; ++ch) {
                const int kk = k0 + 5 * ch;
                #pragma unroll
                for (int q = 0; q < 2; ++q) {
                    const int idx3 = (ij0 + q) * 10 + kk;
                    atomicAdd(&base[D1 + D2 + idx3], sgn * s3[ch * 2 + q]);
                    #pragma unroll
                    for (int l = 0; l < 10; ++l)
                        atomicAdd(&base[D1 + D2 + D3 + idx3 * 10 + l],
                                  sgn * acc[ch * 2 + q][l]);
                }
            }
        }
    }
}

// Stage 1: block sums 32 rows for a float2 d-tile (coalesced), atomically
// accumulates into accvec[DTOT]. Grid: (ceil(5555/256), nrows/32).
__global__ __launch_bounds__(256) void sig_sum_kernel(
    const float* __restrict__ ws, float* __restrict__ accvec)
{
    const int d2 = blockIdx.x * 256 + threadIdx.x;   // DTOT/2 = 5555
    if (d2 >= DTOT / 2) return;
    const float* p = ws + (size_t)(blockIdx.y * 32) * DTOT + 2 * d2;
    float sx = 0.0f, sy = 0.0f;
    #pragma unroll
    for (int r = 0; r < 32; ++r) {
        const float2 v = *(const float2*)(p + (size_t)r * DTOT);
        sx += v.x; sy += v.y;
    }
    atomicAdd(&accvec[2 * d2], sx);
    atomicAdd(&accvec[2 * d2 + 1], sy);
}

// Stage 2: sum of squares -> sumsq; last block writes the norm.
__global__ __launch_bounds__(256) void sig_sumsq_kernel(
    const float* __restrict__ accvec, float* __restrict__ sumsq,
    unsigned int* __restrict__ counter, float* __restrict__ out, int nblocks)
{
    const int d = blockIdx.x * 256 + threadIdx.x;
    float s = 0.0f;
    if (d < DTOT) { float v = accvec[d]; s = v * v; }
    for (int off = 32; off > 0; off >>= 1) s += __shfl_down(s, off, 64);
    __shared__ float red[4];
    __shared__ unsigned int lastflag;
    if ((threadIdx.x & 63) == 0) red[threadIdx.x >> 6] = s;
    __syncthreads();
    if (threadIdx.x == 0) {
        atomicAdd(sumsq, red[0] + red[1] + red[2] + red[3]);
        __threadfence();
        lastflag = (atomicAdd(counter, 1u) == (unsigned int)(nblocks - 1));
    }
    __syncthreads();
    if (threadIdx.x == 0 && lastflag) {
        __threadfence();
        out[0] = sqrtf(*(volatile float*)sumsq) * (1.0f / (float)BSZ);
    }
}

// Fallback reduce for small-ws atomic-replica modes.
__global__ __launch_bounds__(256) void sig_reduce_kernel(
    const float* __restrict__ ws, int nrows, float* __restrict__ sumsq,
    unsigned int* __restrict__ counter, float* __restrict__ out, int nblocks)
{
    const int d = blockIdx.x * 256 + threadIdx.x;
    float s = 0.0f;
    if (d < DTOT) {
        for (int r = 0; r < nrows; ++r) s += ws[(size_t)r * DTOT + d];
        s = s * s;
    }
    for (int off = 32; off > 0; off >>= 1) s += __shfl_down(s, off, 64);
    __shared__ float red[4];
    __shared__ unsigned int lastflag;
    if ((threadIdx.x & 63) == 0) red[threadIdx.x >> 6] = s;
    __syncthreads();
    if (threadIdx.x == 0) {
        atomicAdd(sumsq, red[0] + red[1] + red[2] + red[3]);
        __threadfence();
        lastflag = (atomicAdd(counter, 1u) == (unsigned int)(nblocks - 1));
    }
    __syncthreads();
    if (threadIdx.x == 0 && lastflag) {
        __threadfence();
        out[0] = sqrtf(*(volatile float*)sumsq) * (1.0f / (float)BSZ);
    }
}

extern "C" void kernel_launch(void* const* d_in, const int* in_sizes, int n_in,
                              void* d_out, int out_size, void* d_ws, size_t ws_size,
                              hipStream_t stream) {
    const float* original   = (const float*)d_in[0];
    const float* generated  = (const float*)d_in[1];
    const int*   sample_idx = (const int*)d_in[2];
    float* out = (float*)d_out;
    float* ws  = (float*)d_ws;

    // Layouts:
    //  split: rows [0, 2*NPAIR*DTOT), accvec [+DTOT), sumsq [+1), counter [+1)
    //  store: rows [0, NPAIR*DTOT),   accvec [+DTOT), sumsq [+1), counter [+1)
    const size_t need_split = ((size_t)(2 * NPAIR + 1) * DTOT + 2) * sizeof(float);
    const size_t need_store = ((size_t)(NPAIR + 1) * DTOT + 2) * sizeof(float);

    if (ws_size >= need_split) {
        // Primary: each pass-block writes its own signed row (no atomics).
        float* accvec = ws + (size_t)2 * NPAIR * DTOT;
        float* sumsq  = accvec + DTOT;
        unsigned int* counter = (unsigned int*)(sumsq + 1);
        hipMemsetAsync(accvec, 0, (DTOT + 2) * sizeof(float), stream);
        sig_accum_kernel<<<2 * NPAIR, 256, 0, stream>>>(original, generated,
                                                        sample_idx, ws, 1, 1);
        dim3 g1((DTOT / 2 + 255) / 256, 2 * NPAIR / 32);
        sig_sum_kernel<<<g1, 256, 0, stream>>>(ws, accvec);
        const int nb2 = (DTOT + 255) / 256;
        sig_sumsq_kernel<<<nb2, 256, 0, stream>>>(accvec, sumsq, counter, out, nb2);
    } else if (ws_size >= need_store) {
        // Pair-atomic: the two pass-blocks of a pair accumulate into one row.
        float* accvec = ws + (size_t)NPAIR * DTOT;
        float* sumsq  = accvec + DTOT;
        unsigned int* counter = (unsigned int*)(sumsq + 1);
        hipMemsetAsync(ws, 0, need_store, stream);
        sig_accum_kernel<<<2 * NPAIR, 256, 0, stream>>>(original, generated,
                                                        sample_idx, ws, NPAIR, 0);
        dim3 g1((DTOT / 2 + 255) / 256, NPAIR / 32);
        sig_sum_kernel<<<g1, 256, 0, stream>>>(ws, accvec);
        const int nb2 = (DTOT + 255) / 256;
        sig_sumsq_kernel<<<nb2, 256, 0, stream>>>(accvec, sumsq, counter, out, nb2);
    } else {
        int nrep = 1;
        if (ws_size >= ((size_t)64 * DTOT + 2) * sizeof(float)) nrep = 64;
        else if (ws_size >= ((size_t)8 * DTOT + 2) * sizeof(float)) nrep = 8;
        float* sumsq = ws + (size_t)nrep * DTOT;
        unsigned int* counter = (unsigned int*)(sumsq + 1);
        hipMemsetAsync(ws, 0, ((size_t)nrep * DTOT + 2) * sizeof(float), stream);
        sig_accum_kernel<<<2 * NPAIR, 256, 0, stream>>>(original, generated,
                                                        sample_idx, ws, nrep, 0);
        const int nb2 = (DTOT + 255) / 256;
        sig_reduce_kernel<<<nb2, 256, 0, stream>>>(ws, nrep, sumsq, counter, out, nb2);
    }
}

// Round 3
// 282.928 us; speedup vs baseline: 10.4741x; 1.0030x over previous
//
#include <hip/hip_runtime.h>

// SigWassersteinMetric: depth-4 path signature, C=10, T=256.
//   original: (4096, 256, 10) f32; generated: (1024, 256, 10) f32; sample_idx: (1024,)
//
// ROUND-17: packed-FP32 hot loop (v_pk_fma_f32).
//   - R16 (pass-split grid, 2048 blocks): accum 204us, VALUBusy 82%, VGPR 56.
//     Effective rate 84 TF = 0.82 x m07's measured 103 TF scalar-FMA ceiling:
//     we are pinned on VALU instruction issue. The residual 18% is the wave's
//     own LDS/ctl issue slots.
//   - This round: pair the 54 scalar FMAs/step into ~27 v_pk_fma_f32 via
//     inline asm with op_sel broadcasts (q-pairs share vjp float2; k-channel
//     pairs share (vk0,vk1); level-4 pairs over adjacent l with a3 broadcast
//     from pair halves). Per-step VALU ~61 -> ~37 inst.
//   - DISCRIMINATOR: if m07's 103 TF is an ISSUE limit, accum -> ~140us.
//     If it's a (throttled) FLOP-pipe limit, pk_fma is a null result and we
//     are at the roofline.
//   - VGPR watch: must stay <= 64 (m69 occupancy cliff).
//
// Horner-factored Chen step (verified rounds 2/4-13):
//   A2 = S2 + (S1 + v/4) (x) v/3 ;  B2 = S2 + (S1 + v/3) (x) v/2
//   A3 = S3 + A2 (x) v/2 ;  S4' = S4 + A3 (x) v ;  S3' = S3 + B2 (x) v
//   S2' = S2 + (S1 + v/2) (x) v ;  S1 closed-form in epilogue.
#define T_LEN 256
#define C_DIM 10
#define NSTEP 255
#define BSZ   1024
#define NPAIR 1024
#define D1 10
#define D2 100
#define D3 1000
#define DTOT 11110
#define PATH_ELEMS (T_LEN * C_DIM)   // 2560
#define DX_ELEMS (NSTEP * C_DIM)     // 2550
#define DXROW 12                     // padded dx row stride (48 B, 16B-aligned)

typedef float f32x2 __attribute__((ext_vector_type(2)));
typedef float f32x4 __attribute__((ext_vector_type(4)));

// d += a * b   (elementwise, both halves)
#define PK_FMA(d, a, b) \
    asm("v_pk_fma_f32 %0, %1, %2, %0" : "+v"(d) : "v"(a), "v"(b))
// d += bcast(a.lo) * b
#define PK_FMA_B0(d, a, b) \
    asm("v_pk_fma_f32 %0, %1, %2, %0 op_sel:[0,0,0] op_sel_hi:[0,1,1]" \
        : "+v"(d) : "v"(a), "v"(b))
// d += bcast(a.hi) * b
#define PK_FMA_B1(d, a, b) \
    asm("v_pk_fma_f32 %0, %1, %2, %0 op_sel:[1,0,0] op_sel_hi:[1,1,1]" \
        : "+v"(d) : "v"(a), "v"(b))
// d = bcast(a.lo) * b + c
#define PK_FMA_B0N(d, a, b, c) \
    asm("v_pk_fma_f32 %0, %1, %2, %3 op_sel:[0,0,0] op_sel_hi:[0,1,1]" \
        : "=v"(d) : "v"(a), "v"(b), "v"(c))
// d = bcast(a.hi) * b + c
#define PK_FMA_B1N(d, a, b, c) \
    asm("v_pk_fma_f32 %0, %1, %2, %3 op_sel:[1,0,0] op_sel_hi:[1,1,1]" \
        : "=v"(d) : "v"(a), "v"(b), "v"(c))
// d = a * bcast(b.lo) + c   (src1 broadcast)
#define PK_FMA_S1B0N(d, a, b, c) \
    asm("v_pk_fma_f32 %0, %1, %2, %3 op_sel:[0,0,0] op_sel_hi:[1,0,1]" \
        : "=v"(d) : "v"(a), "v"(b), "v"(c))
// d = a * bcast(b.hi) + c
#define PK_FMA_S1B1N(d, a, b, c) \
    asm("v_pk_fma_f32 %0, %1, %2, %3 op_sel:[0,1,0] op_sel_hi:[1,1,1]" \
        : "=v"(d) : "v"(a), "v"(b), "v"(c))
// d += a * bcast(b.lo)
#define PK_FMA_S1B0(d, a, b) \
    asm("v_pk_fma_f32 %0, %1, %2, %0 op_sel:[0,0,0] op_sel_hi:[1,0,1]" \
        : "+v"(d) : "v"(a), "v"(b))
// d += a * bcast(b.hi)
#define PK_FMA_S1B1(d, a, b) \
    asm("v_pk_fma_f32 %0, %1, %2, %0 op_sel:[0,1,0] op_sel_hi:[1,1,1]" \
        : "+v"(d) : "v"(a), "v"(b))
// d = a * 0.5 (both halves; inline const broadcast via op_sel_hi[1]=0)
#define PK_MUL_HALF(d, a) \
    asm("v_pk_mul_f32 %0, %1, 0.5 op_sel:[0,0] op_sel_hi:[1,0]" \
        : "=v"(d) : "v"(a))

__global__ __launch_bounds__(256)
void sig_accum_kernel(
    const float* __restrict__ original,
    const float* __restrict__ generated,
    const int* __restrict__ sample_idx,
    float* __restrict__ ws, int nrep, int store_mode)
{
    const int tid  = threadIdx.x;
    const int bp   = blockIdx.x;         // 0 .. 2*NPAIR-1
    const int b    = bp >> 1;            // pair index
    const int pass = bp & 1;             // 0 = generated (-), 1 = original (+)
    const float sgn = pass ? 1.0f : -1.0f;

    __shared__ float s_dx[NSTEP * DXROW];  // 12240 B

    const float* path = pass
        ? original + (size_t)sample_idx[b] * PATH_ELEMS
        : generated + (size_t)b * PATH_ELEMS;

    for (int idx = tid; idx < DX_ELEMS; idx += 256) {
        int t = idx / C_DIM, c = idx - t * C_DIM;
        s_dx[t * DXROW + c] = path[idx + C_DIM] - path[idx];
    }
    __syncthreads();

    const int mbase = 2 * tid;               // valid tid<250
    const int k0  = mbase / 100;             // 0..4
    const int ij0 = mbase - k0 * 100;        // even
    const int ia  = ij0 / 10;
    const int j0  = ij0 - ia * 10;           // even -> (j0, j0+1) same decade

    float s1a = 0.0f;
    f32x2 s2p = {0.0f, 0.0f};                 // (q0, q1)
    f32x2 s3p[2] = {{0.0f, 0.0f}, {0.0f, 0.0f}};  // [0]=(q0,q1)@k0, [1]=@k1
    f32x2 acc2[4][5];                         // [0]=q0k0 [1]=q1k0 [2]=q0k1 [3]=q1k1
    #pragma unroll
    for (int r = 0; r < 4; ++r)
        #pragma unroll
        for (int i = 0; i < 5; ++i) acc2[r][i] = (f32x2){0.0f, 0.0f};

    if (tid < 250) {
        const float* vrow = s_dx;
        #pragma unroll 2
        for (int t = 0; t < NSTEP; ++t, vrow += DXROW) {
            const f32x4 va = *(const f32x4*)(vrow);        // v0..v3 (uniform)
            const f32x4 vb = *(const f32x4*)(vrow + 4);    // v4..v7 (uniform)
            const f32x2 vc = *(const f32x2*)(vrow + 8);    // v8,v9  (uniform)
            const f32x2 vjp = *(const f32x2*)(vrow + j0);  // vj for q0,q1
            const float via = vrow[ia];
            f32x2 vkp;
            vkp.x = vrow[k0];
            vkp.y = vrow[k0 + 5];

            const f32x2 vv2[5] = {va.xy, va.zw, vb.xy, vb.zw, vc};

            // scalar prefix terms
            const float t3  = fmaf(via, 0.5f, s1a);
            const float t1b = fmaf(via, 0.25f, s1a) * (1.0f / 3.0f);
            const float t2b = fmaf(via, (1.0f / 3.0f), s1a) * 0.5f;
            f32x2 pA; pA.x = t1b; pA.y = t2b;
            f32x2 pT; pT.x = t3;  pT.y = t3;

            f32x2 vkhp;                       // (vk0*0.5, vk1*0.5)
            PK_MUL_HALF(vkhp, vkp);

            // level 2 (q-pairs)
            f32x2 a2p, b2p;
            PK_FMA_B0N(a2p, pA, vjp, s2p);    // a2_q = t1b*vj_q + s2_q
            PK_FMA_B1N(b2p, pA, vjp, s2p);    // b2_q = t2b*vj_q + s2_q
            PK_FMA_B0(s2p, pT, vjp);          // s2_q += t3*vj_q

            // level 3 (q-pairs, k-channel broadcast from vkp/vkhp halves)
            f32x2 a3xp, a3yp;
            PK_FMA_S1B0N(a3xp, a2p, vkhp, s3p[0]);  // a3_q@k0
            PK_FMA_S1B1N(a3yp, a2p, vkhp, s3p[1]);  // a3_q@k1
            PK_FMA_S1B0(s3p[0], b2p, vkp);          // s3_q@k0 += b2_q*vk0
            PK_FMA_S1B1(s3p[1], b2p, vkp);          // s3_q@k1 += b2_q*vk1

            // level 4: 20 pk-FMAs (a3 broadcast from pair halves)
            #pragma unroll
            for (int i = 0; i < 5; ++i) {
                PK_FMA_B0(acc2[0][i], a3xp, vv2[i]);
                PK_FMA_B1(acc2[1][i], a3xp, vv2[i]);
                PK_FMA_B0(acc2[2][i], a3yp, vv2[i]);
                PK_FMA_B1(acc2[3][i], a3yp, vv2[i]);
            }
            s1a += via;
        }
    }

    // ---- Epilogue: signed single-path row ----
    if (store_mode) {
        float* row = ws + (size_t)bp * DTOT;
        if (tid < D1)
            row[tid] = sgn * (path[(T_LEN - 1) * C_DIM + tid] - path[tid]);
        if (tid < 50) {       // k0 == 0 threads own ij0 = 2*tid
            row[D1 + ij0]     = sgn * s2p[0];
            row[D1 + ij0 + 1] = sgn * s2p[1];
        }
        if (tid < 250) {
            #pragma unroll
            for (int ch = 0; ch < 2; ++ch) {          // ch=0 -> k0, ch=1 -> k0+5
                const int kk = k0 + 5 * ch;
                #pragma unroll
                for (int q = 0; q < 2; ++q) {
                    const int idx3 = (ij0 + q) * 10 + kk;
                    row[D1 + D2 + idx3] = sgn * s3p[ch][q];
                    float* p4 = row + D1 + D2 + D3 + (size_t)idx3 * 10;
                    #pragma unroll
                    for (int i = 0; i < 5; ++i)
                        *(f32x2*)&p4[2 * i] = sgn * acc2[ch * 2 + q][i];
                }
            }
        }
    } else {
        float* base = ws + (size_t)(b % nrep) * DTOT;
        if (tid < D1)
            atomicAdd(&base[tid],
                      sgn * (path[(T_LEN - 1) * C_DIM + tid] - path[tid]));
        if (tid < 50) {
            atomicAdd(&base[D1 + ij0],     sgn * s2p[0]);
            atomicAdd(&base[D1 + ij0 + 1], sgn * s2p[1]);
        }
        if (tid < 250) {
            #pragma unroll
            for (int ch = 0; ch < 2; ++ch) {
                const int kk = k0 + 5 * ch;
                #pragma unroll
                for (int q = 0; q < 2; ++q) {
                    const int idx3 = (ij0 + q) * 10 + kk;
                    atomicAdd(&base[D1 + D2 + idx3], sgn * s3p[ch][q]);
                    #pragma unroll
                    for (int l = 0; l < 10; ++l)
                        atomicAdd(&base[D1 + D2 + D3 + idx3 * 10 + l],
                                  sgn * acc2[ch * 2 + q][l >> 1][l & 1]);
                }
            }
        }
    }
}

// Stage 1: block sums 32 rows for a float2 d-tile (coalesced), atomically
// accumulates into accvec[DTOT]. Grid: (ceil(5555/256), nrows/32).
__global__ __launch_bounds__(256) void sig_sum_kernel(
    const float* __restrict__ ws, float* __restrict__ accvec)
{
    const int d2 = blockIdx.x * 256 + threadIdx.x;   // DTOT/2 = 5555
    if (d2 >= DTOT / 2) return;
    const float* p = ws + (size_t)(blockIdx.y * 32) * DTOT + 2 * d2;
    float sx = 0.0f, sy = 0.0f;
    #pragma unroll
    for (int r = 0; r < 32; ++r) {
        const float2 v = *(const float2*)(p + (size_t)r * DTOT);
        sx += v.x; sy += v.y;
    }
    atomicAdd(&accvec[2 * d2], sx);
    atomicAdd(&accvec[2 * d2 + 1], sy);
}

// Stage 2: sum of squares -> sumsq; last block writes the norm.
__global__ __launch_bounds__(256) void sig_sumsq_kernel(
    const float* __restrict__ accvec, float* __restrict__ sumsq,
    unsigned int* __restrict__ counter, float* __restrict__ out, int nblocks)
{
    const int d = blockIdx.x * 256 + threadIdx.x;
    float s = 0.0f;
    if (d < DTOT) { float v = accvec[d]; s = v * v; }
    for (int off = 32; off > 0; off >>= 1) s += __shfl_down(s, off, 64);
    __shared__ float red[4];
    __shared__ unsigned int lastflag;
    if ((threadIdx.x & 63) == 0) red[threadIdx.x >> 6] = s;
    __syncthreads();
    if (threadIdx.x == 0) {
        atomicAdd(sumsq, red[0] + red[1] + red[2] + red[3]);
        __threadfence();
        lastflag = (atomicAdd(counter, 1u) == (unsigned int)(nblocks - 1));
    }
    __syncthreads();
    if (threadIdx.x == 0 && lastflag) {
        __threadfence();
        out[0] = sqrtf(*(volatile float*)sumsq) * (1.0f / (float)BSZ);
    }
}

// Fallback reduce for small-ws atomic-replica modes.
__global__ __launch_bounds__(256) void sig_reduce_kernel(
    const float* __restrict__ ws, int nrows, float* __restrict__ sumsq,
    unsigned int* __restrict__ counter, float* __restrict__ out, int nblocks)
{
    const int d = blockIdx.x * 256 + threadIdx.x;
    float s = 0.0f;
    if (d < DTOT) {
        for (int r = 0; r < nrows; ++r) s += ws[(size_t)r * DTOT + d];
        s = s * s;
    }
    for (int off = 32; off > 0; off >>= 1) s += __shfl_down(s, off, 64);
    __shared__ float red[4];
    __shared__ unsigned int lastflag;
    if ((threadIdx.x & 63) == 0) red[threadIdx.x >> 6] = s;
    __syncthreads();
    if (threadIdx.x == 0) {
        atomicAdd(sumsq, red[0] + red[1] + red[2] + red[3]);
        __threadfence();
        lastflag = (atomicAdd(counter, 1u) == (unsigned int)(nblocks - 1));
    }
    __syncthreads();
    if (threadIdx.x == 0 && lastflag) {
        __threadfence();
        out[0] = sqrtf(*(volatile float*)sumsq) * (1.0f / (float)BSZ);
    }
}

extern "C" void kernel_launch(void* const* d_in, const int* in_sizes, int n_in,
                              void* d_out, int out_size, void* d_ws, size_t ws_size,
                              hipStream_t stream) {
    const float* original   = (const float*)d_in[0];
    const float* generated  = (const float*)d_in[1];
    const int*   sample_idx = (const int*)d_in[2];
    float* out = (float*)d_out;
    float* ws  = (float*)d_ws;

    // Layouts:
    //  split: rows [0, 2*NPAIR*DTOT), accvec [+DTOT), sumsq [+1), counter [+1)
    //  store: rows [0, NPAIR*DTOT),   accvec [+DTOT), sumsq [+1), counter [+1)
    const size_t need_split = ((size_t)(2 * NPAIR + 1) * DTOT + 2) * sizeof(float);
    const size_t need_store = ((size_t)(NPAIR + 1) * DTOT + 2) * sizeof(float);

    if (ws_size >= need_split) {
        // Primary: each pass-block writes its own signed row (no atomics).
        float* accvec = ws + (size_t)2 * NPAIR * DTOT;
        float* sumsq  = accvec + DTOT;
        unsigned int* counter = (unsigned int*)(sumsq + 1);
        hipMemsetAsync(accvec, 0, (DTOT + 2) * sizeof(float), stream);
        sig_accum_kernel<<<2 * NPAIR, 256, 0, stream>>>(original, generated,
                                                        sample_idx, ws, 1, 1);
        dim3 g1((DTOT / 2 + 255) / 256, 2 * NPAIR / 32);
        sig_sum_kernel<<<g1, 256, 0, stream>>>(ws, accvec);
        const int nb2 = (DTOT + 255) / 256;
        sig_sumsq_kernel<<<nb2, 256, 0, stream>>>(accvec, sumsq, counter, out, nb2);
    } else if (ws_size >= need_store) {
        // Pair-atomic: the two pass-blocks of a pair accumulate into one row.
        float* accvec = ws + (size_t)NPAIR * DTOT;
        float* sumsq  = accvec + DTOT;
        unsigned int* counter = (unsigned int*)(sumsq + 1);
        hipMemsetAsync(ws, 0, need_store, stream);
        sig_accum_kernel<<<2 * NPAIR, 256, 0, stream>>>(original, generated,
                                                        sample_idx, ws, NPAIR, 0);
        dim3 g1((DTOT / 2 + 255) / 256, NPAIR / 32);
        sig_sum_kernel<<<g1, 256, 0, stream>>>(ws, accvec);
        const int nb2 = (DTOT + 255) / 256;
        sig_sumsq_kernel<<<nb2, 256, 0, stream>>>(accvec, sumsq, counter, out, nb2);
    } else {
        int nrep = 1;
        if (ws_size >= ((size_t)64 * DTOT + 2) * sizeof(float)) nrep = 64;
        else if (ws_size >= ((size_t)8 * DTOT + 2) * sizeof(float)) nrep = 8;
        float* sumsq = ws + (size_t)nrep * DTOT;
        unsigned int* counter = (unsigned int*)(sumsq + 1);
        hipMemsetAsync(ws, 0, ((size_t)nrep * DTOT + 2) * sizeof(float), stream);
        sig_accum_kernel<<<2 * NPAIR, 256, 0, stream>>>(original, generated,
                                                        sample_idx, ws, nrep, 0);
        const int nb2 = (DTOT + 255) / 256;
        sig_reduce_kernel<<<nb2, 256, 0, stream>>>(ws, nrep, sumsq, counter, out, nb2);
    }
}